// Round 2
// baseline (10535.886 us; speedup 1.0000x reference)
//
#include <hip/hip_runtime.h>

// LSTM B=64,T=512,I=256,H=512,L=2,O=128. fp32 in/out, bf16 MFMA compute.
//
// R2: single persistent kernel (64 blocks, 1/CU guaranteed by size), hand-rolled
// device-scope grid barrier per timestep. Layer1 pipelined 1 step behind layer0.
// Weights preloaded into registers (short8 bf[32] per lane, ~128 VGPRs), c-state
// in registers, h planes ping-pong in ws, x transposed to [T][B][I] bf16.
//
// Block b: layer=b>>5, n2=b&31 -> gate cols n2*16..+16 (all 4 strips), all 64
// batches. Wave wv = gate strip (i/f/g/o); 4 batch-tiles of 16 per wave.
//
// ws layout (bytes):
//   0         xT_bf16 [512][64][256] bf16   16,777,216   (x transposed t-major)
//   16777216  Wpack0  [2048][768]    bf16    3,145,728
//   19922944  Wpack1  [2048][1024]   bf16    4,194,304
//   24117248  h0 planes[2][64][512]  bf16      131,072
//   24248320  h1 planes[2][64][512]  bf16      131,072
//   24379392  flags   [64] uint                    256

#define B_  64
#define T_  512
#define I0_ 256
#define H_  512
#define NBLK 64

typedef unsigned short ushort_t;
typedef __attribute__((ext_vector_type(8))) short   short8;
typedef __attribute__((ext_vector_type(4))) float   float4v;

__device__ __forceinline__ unsigned short f2bf(float f) {
    unsigned int u = __builtin_bit_cast(unsigned int, f);
    u += 0x7fffu + ((u >> 16) & 1u);           // RTNE
    return (unsigned short)(u >> 16);
}

// ---- prologue: x fp32 [B][T][I] -> bf16 transposed [T][B][I] -------------
__global__ void conv_x(const float* __restrict__ x, ushort_t* __restrict__ xb) {
    size_t idx4 = ((size_t)blockIdx.x * 256 + threadIdx.x) * 4;   // flat in [B][T][I]
    float4 v = *(const float4*)(x + idx4);
    size_t b = idx4 >> 17;              // / (T*I)
    size_t rem = idx4 & 131071;
    size_t t = rem >> 8;
    size_t i = rem & 255;
    ushort4 o;
    o.x = f2bf(v.x); o.y = f2bf(v.y); o.z = f2bf(v.z); o.w = f2bf(v.w);
    *(ushort4*)(xb + (((t * B_) + b) << 8) + i) = o;
}

// ---- prologue: pack [W_ih | W_hh] -> bf16, rows grouped per col-group ----
// packed row p = n*64 + strip*16 + jj  <->  gate row g = strip*512 + n*16 + jj
__global__ void pack_w(const float* __restrict__ wih0, const float* __restrict__ whh0,
                       const float* __restrict__ wih1, const float* __restrict__ whh1,
                       ushort_t* __restrict__ wp0, ushort_t* __restrict__ wp1) {
    int p = blockIdx.x;
    int layer = p >> 11;
    int row = p & 2047;
    int n = row >> 6, rem = row & 63;
    int st = rem >> 4, jj = rem & 15;
    int g = st * 512 + n * 16 + jj;
    if (layer == 0) {
        for (int k = threadIdx.x; k < 768; k += 256) {
            float v = (k < 256) ? wih0[(size_t)g * 256 + k]
                                : whh0[(size_t)g * 512 + (k - 256)];
            wp0[(size_t)row * 768 + k] = f2bf(v);
        }
    } else {
        for (int k = threadIdx.x; k < 1024; k += 256) {
            float v = (k < 512) ? wih1[(size_t)g * 512 + k]
                                : whh1[(size_t)g * 512 + (k - 512)];
            wp1[(size_t)row * 1024 + k] = f2bf(v);
        }
    }
}

// ---- prologue: zero h planes + flags (262400 B from h0 base) -------------
__global__ void zero_ws(uint4* p) {
    size_t i = (size_t)blockIdx.x * 256 + threadIdx.x;
    if (i < 16400) p[i] = uint4{0, 0, 0, 0};
}

// ---- persistent LSTM kernel ----------------------------------------------
__global__ __launch_bounds__(256, 1) void lstm_persist(
    const ushort_t* __restrict__ xbf,
    const ushort_t* __restrict__ wp0,
    const ushort_t* __restrict__ wp1,
    ushort_t* __restrict__ h0,
    ushort_t* __restrict__ h1,
    const float* __restrict__ bi0, const float* __restrict__ bh0,
    const float* __restrict__ bi1, const float* __restrict__ bh1,
    float* __restrict__ dout,
    unsigned* __restrict__ flags)
{
    const int blk   = blockIdx.x;
    const int layer = blk >> 5;
    const int n2    = blk & 31;
    const int tid   = threadIdx.x;
    const int lane  = tid & 63;
    const int wv    = tid >> 6;      // gate strip 0=i 1=f 2=g 3=o
    const int lr    = lane & 15;
    const int lq    = lane >> 4;

    // ---- preload this wave's weight slice into registers ----
    short8 bf[32];
    if (layer) {
        const ushort_t* bp = wp1 + (size_t)(n2 * 64 + wv * 16 + lr) * 1024 + lq * 8;
        #pragma unroll
        for (int kc = 0; kc < 32; ++kc) bf[kc] = *(const short8*)(bp + kc * 32);
    } else {
        const ushort_t* bp = wp0 + (size_t)(n2 * 64 + wv * 16 + lr) * 768 + lq * 8;
        #pragma unroll
        for (int kc = 0; kc < 24; ++kc) bf[kc] = *(const short8*)(bp + kc * 32);
    }

    __shared__ float xch[4][64][16];

    // ---- epilogue-role constants (thread owns col j, batches b4..b4+3) ----
    const int j   = tid & 15;
    const int b4  = (tid >> 4) * 4;
    const int col = n2 * 16 + j;
    const float* bi = layer ? bi1 : bi0;
    const float* bh = layer ? bh1 : bh0;
    const float bias_i = bi[col]        + bh[col];
    const float bias_f = bi[512 + col]  + bh[512 + col];
    const float bias_g = bi[1024 + col] + bh[1024 + col];
    const float bias_o = bi[1536 + col] + bh[1536 + col];
    float creg[4] = {0.f, 0.f, 0.f, 0.f};

    #pragma unroll 1
    for (int s = 0; s < 513; ++s) {
        const bool work = layer ? (s >= 1) : (s < 512);
        const int  t    = layer ? (s - 1) : s;
        const int  rp   = (s + 1) & 1;
        const int  wpar = s & 1;

        if (work) {
            float4v acc0 = {0.f,0.f,0.f,0.f}, acc1 = {0.f,0.f,0.f,0.f};
            float4v acc2 = {0.f,0.f,0.f,0.f}, acc3 = {0.f,0.f,0.f,0.f};

            if (layer == 0) {
                const ushort_t* aB = xbf + ((size_t)s * B_ + lr) * I0_ + lq * 8;
                #pragma unroll
                for (int kc = 0; kc < 8; ++kc) {
                    short8 a0 = *(const short8*)(aB + kc * 32);
                    short8 a1 = *(const short8*)(aB + 16 * I0_ + kc * 32);
                    short8 a2 = *(const short8*)(aB + 32 * I0_ + kc * 32);
                    short8 a3 = *(const short8*)(aB + 48 * I0_ + kc * 32);
                    acc0 = __builtin_amdgcn_mfma_f32_16x16x32_bf16(a0, bf[kc], acc0, 0, 0, 0);
                    acc1 = __builtin_amdgcn_mfma_f32_16x16x32_bf16(a1, bf[kc], acc1, 0, 0, 0);
                    acc2 = __builtin_amdgcn_mfma_f32_16x16x32_bf16(a2, bf[kc], acc2, 0, 0, 0);
                    acc3 = __builtin_amdgcn_mfma_f32_16x16x32_bf16(a3, bf[kc], acc3, 0, 0, 0);
                }
                const ushort_t* hR = h0 + rp * (B_ * H_) + (size_t)lr * H_ + lq * 8;
                #pragma unroll
                for (int kc = 0; kc < 16; ++kc) {
                    short8 a0 = *(const short8*)(hR + kc * 32);
                    short8 a1 = *(const short8*)(hR + 16 * H_ + kc * 32);
                    short8 a2 = *(const short8*)(hR + 32 * H_ + kc * 32);
                    short8 a3 = *(const short8*)(hR + 48 * H_ + kc * 32);
                    acc0 = __builtin_amdgcn_mfma_f32_16x16x32_bf16(a0, bf[8 + kc], acc0, 0, 0, 0);
                    acc1 = __builtin_amdgcn_mfma_f32_16x16x32_bf16(a1, bf[8 + kc], acc1, 0, 0, 0);
                    acc2 = __builtin_amdgcn_mfma_f32_16x16x32_bf16(a2, bf[8 + kc], acc2, 0, 0, 0);
                    acc3 = __builtin_amdgcn_mfma_f32_16x16x32_bf16(a3, bf[8 + kc], acc3, 0, 0, 0);
                }
            } else {
                const ushort_t* hA = h0 + rp * (B_ * H_) + (size_t)lr * H_ + lq * 8;
                #pragma unroll
                for (int kc = 0; kc < 16; ++kc) {
                    short8 a0 = *(const short8*)(hA + kc * 32);
                    short8 a1 = *(const short8*)(hA + 16 * H_ + kc * 32);
                    short8 a2 = *(const short8*)(hA + 32 * H_ + kc * 32);
                    short8 a3 = *(const short8*)(hA + 48 * H_ + kc * 32);
                    acc0 = __builtin_amdgcn_mfma_f32_16x16x32_bf16(a0, bf[kc], acc0, 0, 0, 0);
                    acc1 = __builtin_amdgcn_mfma_f32_16x16x32_bf16(a1, bf[kc], acc1, 0, 0, 0);
                    acc2 = __builtin_amdgcn_mfma_f32_16x16x32_bf16(a2, bf[kc], acc2, 0, 0, 0);
                    acc3 = __builtin_amdgcn_mfma_f32_16x16x32_bf16(a3, bf[kc], acc3, 0, 0, 0);
                }
                const ushort_t* hB = h1 + wpar * (B_ * H_) + (size_t)lr * H_ + lq * 8;
                #pragma unroll
                for (int kc = 0; kc < 16; ++kc) {
                    short8 a0 = *(const short8*)(hB + kc * 32);
                    short8 a1 = *(const short8*)(hB + 16 * H_ + kc * 32);
                    short8 a2 = *(const short8*)(hB + 32 * H_ + kc * 32);
                    short8 a3 = *(const short8*)(hB + 48 * H_ + kc * 32);
                    acc0 = __builtin_amdgcn_mfma_f32_16x16x32_bf16(a0, bf[16 + kc], acc0, 0, 0, 0);
                    acc1 = __builtin_amdgcn_mfma_f32_16x16x32_bf16(a1, bf[16 + kc], acc1, 0, 0, 0);
                    acc2 = __builtin_amdgcn_mfma_f32_16x16x32_bf16(a2, bf[16 + kc], acc2, 0, 0, 0);
                    acc3 = __builtin_amdgcn_mfma_f32_16x16x32_bf16(a3, bf[16 + kc], acc3, 0, 0, 0);
                }
            }
            // D layout: col=lane&15, row=(lane>>4)*4+reg  (row = batch within tile)
            #pragma unroll
            for (int r = 0; r < 4; ++r) {
                xch[wv][ 0 + lq * 4 + r][lr] = acc0[r];
                xch[wv][16 + lq * 4 + r][lr] = acc1[r];
                xch[wv][32 + lq * 4 + r][lr] = acc2[r];
                xch[wv][48 + lq * 4 + r][lr] = acc3[r];
            }
        }
        __syncthreads();

        if (work) {
            ushort_t* hw = layer ? (h1 + rp * (B_ * H_)) : (h0 + wpar * (B_ * H_));
            #pragma unroll
            for (int u = 0; u < 4; ++u) {
                const int batch = b4 + u;
                float iv = xch[0][batch][j] + bias_i;
                float fv = xch[1][batch][j] + bias_f;
                float gv = xch[2][batch][j] + bias_g;
                float ov = xch[3][batch][j] + bias_o;
                float ig = 1.f / (1.f + __expf(-iv));
                float fg = 1.f / (1.f + __expf(-fv));
                float og = 1.f / (1.f + __expf(-ov));
                float gg = tanhf(gv);
                float cn = fg * creg[u] + ig * gg;
                float hn = og * tanhf(cn);
                creg[u] = cn;
                hw[batch * H_ + col] = f2bf(hn);
                if (layer) dout[8192 + ((size_t)batch * T_ + t) * H_ + col] = hn;
                if (t == 511) {
                    dout[16785408 + (size_t)layer * (B_ * H_) + batch * H_ + col] = hn;
                    dout[16850944 + (size_t)layer * (B_ * H_) + batch * H_ + col] = cn;
                }
            }
        }

        // ---- grid barrier (device scope) ----
        __syncthreads();   // all waves' stores drained (vmcnt0 before s_barrier)
        if (tid == 0) {
            __threadfence();   // wb local L2 -> MALL (release)
            __hip_atomic_store(&flags[blk], (unsigned)(s + 1),
                               __ATOMIC_RELAXED, __HIP_MEMORY_SCOPE_AGENT);
        }
        if (tid < NBLK) {
            while (__hip_atomic_load(&flags[tid], __ATOMIC_RELAXED,
                                     __HIP_MEMORY_SCOPE_AGENT) < (unsigned)(s + 1)) { }
            __threadfence();   // inv L1/L2 (acquire) — wave 0, covers whole CU
        }
        __syncthreads();
    }
}

// ---- final projection: out = h1T @ W_out^T + b_out -----------------------
__global__ void out_gemm(const float* __restrict__ h1T, const float* __restrict__ wout,
                         const float* __restrict__ bout, float* __restrict__ out) {
    int b = blockIdx.x, o = threadIdx.x;
    const float* hr = h1T + (size_t)b * 512;
    const float* wr = wout + (size_t)o * 512;
    float acc = bout[o];
    #pragma unroll 8
    for (int k = 0; k < 512; ++k) acc += hr[k] * wr[k];
    out[b * 128 + o] = acc;
}

extern "C" void kernel_launch(void* const* d_in, const int* in_sizes, int n_in,
                              void* d_out, int out_size, void* d_ws, size_t ws_size,
                              hipStream_t stream)
{
    const float* x    = (const float*)d_in[0];
    const float* wih0 = (const float*)d_in[1];
    const float* whh0 = (const float*)d_in[2];
    const float* bih0 = (const float*)d_in[3];
    const float* bhh0 = (const float*)d_in[4];
    const float* wih1 = (const float*)d_in[5];
    const float* whh1 = (const float*)d_in[6];
    const float* bih1 = (const float*)d_in[7];
    const float* bhh1 = (const float*)d_in[8];
    const float* wout = (const float*)d_in[9];
    const float* bout = (const float*)d_in[10];
    float* out = (float*)d_out;

    char* ws = (char*)d_ws;
    ushort_t* xbf   = (ushort_t*)(ws);
    ushort_t* wp0   = (ushort_t*)(ws + 16777216);
    ushort_t* wp1   = (ushort_t*)(ws + 19922944);
    ushort_t* h0    = (ushort_t*)(ws + 24117248);
    ushort_t* h1    = (ushort_t*)(ws + 24248320);
    unsigned* flags = (unsigned*)(ws + 24379392);

    conv_x<<<8192, 256, 0, stream>>>(x, xbf);
    pack_w<<<4096, 256, 0, stream>>>(wih0, whh0, wih1, whh1, wp0, wp1);
    zero_ws<<<65, 256, 0, stream>>>((uint4*)(ws + 24117248));

    lstm_persist<<<NBLK, 256, 0, stream>>>(xbf, wp0, wp1, h0, h1,
                                           bih0, bhh0, bih1, bhh1, out, flags);

    out_gemm<<<64, 128, 0, stream>>>(out + 16785408 + B_ * H_, wout, bout, out);
}

// Round 4
// 6147.631 us; speedup vs baseline: 1.7138x; 1.7138x over previous
//
#include <hip/hip_runtime.h>

// LSTM B=64,T=512,I=256,H=512,L=2,O=128. fp32 in/out, bf16 MFMA compute.
//
// R4 = R3 with the nontemporal-store type fixed (ext_vector_type, not HIP float4).
// Persistent kernel, flag-based grid sync with NO cache fences.
// h exchange through the coherence point (MALL):
//   producers: global_store sc0 sc1 (write-through), vmcnt drain, flag sc0 sc1
//   consumers: poll flags sc0 sc1, stage h planes into LDS via
//              global_load_dwordx4 sc0 sc1 (bypass L1/L2 -> always fresh)
// x/weights/biases remain normally cached (never invalidated).
//
// Block b: layer=b>>5, n2=b&31 -> 16 gate-cols x 4 strips, all 64 batches.
// Wave wv = gate strip; 4 batch-tiles of 16. Weights in registers.
// LDS: buf0 64KB (h plane), buf1 64KB (layer1 second plane), xch 16KB
//      = 147456 B dynamic (hipFuncSetAttribute).
//
// ws layout (bytes):
//   0         xT_bf16 [512][64][256] bf16   16,777,216
//   16777216  Wpack0  [2048][768]    bf16    3,145,728
//   19922944  Wpack1  [2048][1024]   bf16    4,194,304
//   24117248  h0 planes[2][64][512]  bf16      131,072
//   24248320  h1 planes[2][64][512]  bf16      131,072
//   24379392  flags   [64] uint                    256

#define B_  64
#define T_  512
#define I0_ 256
#define H_  512
#define NBLK 64

typedef unsigned short ushort_t;
typedef __attribute__((ext_vector_type(8))) short        short8;
typedef __attribute__((ext_vector_type(4))) float        float4v;
typedef __attribute__((ext_vector_type(4))) unsigned int u32x4;
typedef __attribute__((ext_vector_type(2))) unsigned int u32x2;

__device__ __forceinline__ unsigned short f2bf(float f) {
    unsigned int u = __builtin_bit_cast(unsigned int, f);
    u += 0x7fffu + ((u >> 16) & 1u);           // RTNE
    return (unsigned short)(u >> 16);
}

// ---- prologue: x fp32 [B][T][I] -> bf16 transposed [T][B][I] -------------
__global__ void conv_x(const float* __restrict__ x, ushort_t* __restrict__ xb) {
    size_t idx4 = ((size_t)blockIdx.x * 256 + threadIdx.x) * 4;
    float4 v = *(const float4*)(x + idx4);
    size_t b = idx4 >> 17;
    size_t rem = idx4 & 131071;
    size_t t = rem >> 8;
    size_t i = rem & 255;
    ushort4 o;
    o.x = f2bf(v.x); o.y = f2bf(v.y); o.z = f2bf(v.z); o.w = f2bf(v.w);
    *(ushort4*)(xb + (((t * B_) + b) << 8) + i) = o;
}

// ---- prologue: pack [W_ih | W_hh] -> bf16, rows grouped per col-group ----
__global__ void pack_w(const float* __restrict__ wih0, const float* __restrict__ whh0,
                       const float* __restrict__ wih1, const float* __restrict__ whh1,
                       ushort_t* __restrict__ wp0, ushort_t* __restrict__ wp1) {
    int p = blockIdx.x;
    int layer = p >> 11;
    int row = p & 2047;
    int n = row >> 6, rem = row & 63;
    int st = rem >> 4, jj = rem & 15;
    int g = st * 512 + n * 16 + jj;
    if (layer == 0) {
        for (int k = threadIdx.x; k < 768; k += 256) {
            float v = (k < 256) ? wih0[(size_t)g * 256 + k]
                                : whh0[(size_t)g * 512 + (k - 256)];
            wp0[(size_t)row * 768 + k] = f2bf(v);
        }
    } else {
        for (int k = threadIdx.x; k < 1024; k += 256) {
            float v = (k < 512) ? wih1[(size_t)g * 512 + k]
                                : whh1[(size_t)g * 512 + (k - 512)];
            wp1[(size_t)row * 1024 + k] = f2bf(v);
        }
    }
}

// ---- prologue: zero h planes + flags -------------------------------------
__global__ void zero_ws(uint4* p) {
    size_t i = (size_t)blockIdx.x * 256 + threadIdx.x;
    if (i < 16400) p[i] = uint4{0, 0, 0, 0};
}

// ---- system-scope (coherence-point) helpers ------------------------------
__device__ __forceinline__ void store8_sys(void* p, u32x2 v) {
    asm volatile("global_store_dwordx2 %0, %1, off sc0 sc1" :: "v"(p), "v"(v) : "memory");
}
__device__ __forceinline__ unsigned load_flag_sys(const unsigned* p) {
    unsigned r;
    asm volatile("global_load_dword %0, %1, off sc0 sc1\n\ts_waitcnt vmcnt(0)"
                 : "=v"(r) : "v"(p) : "memory");
    return r;
}

// stage one 64KB h plane (64 rows x 512 cols bf16) into LDS, chunked layout:
// LDS uint4-index = (k/8)*64 + row. Thread: row=tid>>2, k-span=(tid&3)*128.
__device__ __forceinline__ void stage_plane(const ushort_t* plane, ushort_t* lds, int tid) {
    const ushort_t* ga = plane + (tid >> 2) * 512 + (tid & 3) * 128;
    u32x4 t0,t1,t2,t3,t4,t5,t6,t7,t8,t9,t10,t11,t12,t13,t14,t15;
    asm volatile(
        "global_load_dwordx4 %0,  %16, off sc0 sc1\n\t"
        "global_load_dwordx4 %1,  %16, off offset:16 sc0 sc1\n\t"
        "global_load_dwordx4 %2,  %16, off offset:32 sc0 sc1\n\t"
        "global_load_dwordx4 %3,  %16, off offset:48 sc0 sc1\n\t"
        "global_load_dwordx4 %4,  %16, off offset:64 sc0 sc1\n\t"
        "global_load_dwordx4 %5,  %16, off offset:80 sc0 sc1\n\t"
        "global_load_dwordx4 %6,  %16, off offset:96 sc0 sc1\n\t"
        "global_load_dwordx4 %7,  %16, off offset:112 sc0 sc1\n\t"
        "global_load_dwordx4 %8,  %16, off offset:128 sc0 sc1\n\t"
        "global_load_dwordx4 %9,  %16, off offset:144 sc0 sc1\n\t"
        "global_load_dwordx4 %10, %16, off offset:160 sc0 sc1\n\t"
        "global_load_dwordx4 %11, %16, off offset:176 sc0 sc1\n\t"
        "global_load_dwordx4 %12, %16, off offset:192 sc0 sc1\n\t"
        "global_load_dwordx4 %13, %16, off offset:208 sc0 sc1\n\t"
        "global_load_dwordx4 %14, %16, off offset:224 sc0 sc1\n\t"
        "global_load_dwordx4 %15, %16, off offset:240 sc0 sc1\n\t"
        "s_waitcnt vmcnt(0)"
        : "=&v"(t0),"=&v"(t1),"=&v"(t2),"=&v"(t3),"=&v"(t4),"=&v"(t5),"=&v"(t6),"=&v"(t7),
          "=&v"(t8),"=&v"(t9),"=&v"(t10),"=&v"(t11),"=&v"(t12),"=&v"(t13),"=&v"(t14),"=&v"(t15)
        : "v"(ga)
        : "memory");
    u32x4* lw = (u32x4*)lds + (tid & 3) * 1024 + (tid >> 2);
    lw[0*64]=t0;  lw[1*64]=t1;  lw[2*64]=t2;  lw[3*64]=t3;
    lw[4*64]=t4;  lw[5*64]=t5;  lw[6*64]=t6;  lw[7*64]=t7;
    lw[8*64]=t8;  lw[9*64]=t9;  lw[10*64]=t10; lw[11*64]=t11;
    lw[12*64]=t12; lw[13*64]=t13; lw[14*64]=t14; lw[15*64]=t15;
}

// ---- persistent LSTM kernel ----------------------------------------------
extern __shared__ ushort_t smem[];

__global__ __launch_bounds__(256, 1) void lstm_persist(
    const ushort_t* __restrict__ xbf,
    const ushort_t* __restrict__ wp0,
    const ushort_t* __restrict__ wp1,
    ushort_t* __restrict__ h0,
    ushort_t* __restrict__ h1,
    const float* __restrict__ bi0, const float* __restrict__ bh0,
    const float* __restrict__ bi1, const float* __restrict__ bh1,
    float* __restrict__ dout,
    unsigned* __restrict__ flags)
{
    const int blk   = blockIdx.x;
    const int layer = blk >> 5;
    const int n2    = blk & 31;
    const int tid   = threadIdx.x;
    const int lane  = tid & 63;
    const int wv    = tid >> 6;      // gate strip 0=i 1=f 2=g 3=o
    const int lr    = lane & 15;
    const int lq    = lane >> 4;

    ushort_t* buf0 = smem;                   // 64KB
    ushort_t* buf1 = smem + 32768;           // 64KB
    float*    xchf = (float*)(smem + 65536); // 16KB

    // ---- preload this wave's weight slice into registers ----
    short8 bf[32];
    if (layer) {
        const ushort_t* bp = wp1 + (size_t)(n2 * 64 + wv * 16 + lr) * 1024 + lq * 8;
        #pragma unroll
        for (int kc = 0; kc < 32; ++kc) bf[kc] = *(const short8*)(bp + kc * 32);
    } else {
        const ushort_t* bp = wp0 + (size_t)(n2 * 64 + wv * 16 + lr) * 768 + lq * 8;
        #pragma unroll
        for (int kc = 0; kc < 24; ++kc) bf[kc] = *(const short8*)(bp + kc * 32);
    }

    // ---- epilogue role: thread owns batch b_ep, 4 cols q4..q4+3 ----------
    const int b_ep = tid >> 2;
    const int q4   = (tid & 3) * 4;
    const int col0 = n2 * 16 + q4;
    const float* bi = layer ? bi1 : bi0;
    const float* bh = layer ? bh1 : bh0;
    float bias[4][4];
    #pragma unroll
    for (int g = 0; g < 4; ++g)
        #pragma unroll
        for (int r = 0; r < 4; ++r)
            bias[g][r] = bi[g * 512 + col0 + r] + bh[g * 512 + col0 + r];
    float creg[4] = {0.f, 0.f, 0.f, 0.f};

    #pragma unroll 1
    for (int s = 0; s < 513; ++s) {
        const bool work = layer ? (s >= 1) : (s < 512);
        const int  t    = layer ? (s - 1) : s;
        const int  rp   = (s + 1) & 1;
        const int  wpar = s & 1;

        // ---- stage h planes into LDS (coherence-point loads) ----
        if (work) {
            stage_plane(h0 + rp * (B_ * H_), buf0, tid);
            if (layer) stage_plane(h1 + wpar * (B_ * H_), buf1, tid);
        }
        __syncthreads();

        if (work) {
            float4v acc0 = {0.f,0.f,0.f,0.f}, acc1 = {0.f,0.f,0.f,0.f};
            float4v acc2 = {0.f,0.f,0.f,0.f}, acc3 = {0.f,0.f,0.f,0.f};

            if (layer == 0) {
                const ushort_t* aB = xbf + ((size_t)s * B_ + lr) * I0_ + lq * 8;
                #pragma unroll
                for (int kc = 0; kc < 8; ++kc) {
                    short8 a0 = *(const short8*)(aB + kc * 32);
                    short8 a1 = *(const short8*)(aB + 16 * I0_ + kc * 32);
                    short8 a2 = *(const short8*)(aB + 32 * I0_ + kc * 32);
                    short8 a3 = *(const short8*)(aB + 48 * I0_ + kc * 32);
                    acc0 = __builtin_amdgcn_mfma_f32_16x16x32_bf16(a0, bf[kc], acc0, 0, 0, 0);
                    acc1 = __builtin_amdgcn_mfma_f32_16x16x32_bf16(a1, bf[kc], acc1, 0, 0, 0);
                    acc2 = __builtin_amdgcn_mfma_f32_16x16x32_bf16(a2, bf[kc], acc2, 0, 0, 0);
                    acc3 = __builtin_amdgcn_mfma_f32_16x16x32_bf16(a3, bf[kc], acc3, 0, 0, 0);
                }
                #pragma unroll
                for (int c = 0; c < 16; ++c) {
                    const int base = ((c * 4 + lq) * 64 + lr) * 8;
                    short8 a0 = *(const short8*)(buf0 + base);
                    short8 a1 = *(const short8*)(buf0 + base + 16 * 8);
                    short8 a2 = *(const short8*)(buf0 + base + 32 * 8);
                    short8 a3 = *(const short8*)(buf0 + base + 48 * 8);
                    acc0 = __builtin_amdgcn_mfma_f32_16x16x32_bf16(a0, bf[8 + c], acc0, 0, 0, 0);
                    acc1 = __builtin_amdgcn_mfma_f32_16x16x32_bf16(a1, bf[8 + c], acc1, 0, 0, 0);
                    acc2 = __builtin_amdgcn_mfma_f32_16x16x32_bf16(a2, bf[8 + c], acc2, 0, 0, 0);
                    acc3 = __builtin_amdgcn_mfma_f32_16x16x32_bf16(a3, bf[8 + c], acc3, 0, 0, 0);
                }
            } else {
                #pragma unroll
                for (int c = 0; c < 16; ++c) {
                    const int base = ((c * 4 + lq) * 64 + lr) * 8;
                    short8 a0 = *(const short8*)(buf0 + base);
                    short8 a1 = *(const short8*)(buf0 + base + 16 * 8);
                    short8 a2 = *(const short8*)(buf0 + base + 32 * 8);
                    short8 a3 = *(const short8*)(buf0 + base + 48 * 8);
                    acc0 = __builtin_amdgcn_mfma_f32_16x16x32_bf16(a0, bf[c], acc0, 0, 0, 0);
                    acc1 = __builtin_amdgcn_mfma_f32_16x16x32_bf16(a1, bf[c], acc1, 0, 0, 0);
                    acc2 = __builtin_amdgcn_mfma_f32_16x16x32_bf16(a2, bf[c], acc2, 0, 0, 0);
                    acc3 = __builtin_amdgcn_mfma_f32_16x16x32_bf16(a3, bf[c], acc3, 0, 0, 0);
                }
                #pragma unroll
                for (int c = 0; c < 16; ++c) {
                    const int base = ((c * 4 + lq) * 64 + lr) * 8;
                    short8 a0 = *(const short8*)(buf1 + base);
                    short8 a1 = *(const short8*)(buf1 + base + 16 * 8);
                    short8 a2 = *(const short8*)(buf1 + base + 32 * 8);
                    short8 a3 = *(const short8*)(buf1 + base + 48 * 8);
                    acc0 = __builtin_amdgcn_mfma_f32_16x16x32_bf16(a0, bf[16 + c], acc0, 0, 0, 0);
                    acc1 = __builtin_amdgcn_mfma_f32_16x16x32_bf16(a1, bf[16 + c], acc1, 0, 0, 0);
                    acc2 = __builtin_amdgcn_mfma_f32_16x16x32_bf16(a2, bf[16 + c], acc2, 0, 0, 0);
                    acc3 = __builtin_amdgcn_mfma_f32_16x16x32_bf16(a3, bf[16 + c], acc3, 0, 0, 0);
                }
            }
            // D layout: col=lane&15, row=(lane>>4)*4+reg
            #pragma unroll
            for (int r = 0; r < 4; ++r) {
                xchf[wv * 1024 + ( 0 + lq * 4 + r) * 16 + lr] = acc0[r];
                xchf[wv * 1024 + (16 + lq * 4 + r) * 16 + lr] = acc1[r];
                xchf[wv * 1024 + (32 + lq * 4 + r) * 16 + lr] = acc2[r];
                xchf[wv * 1024 + (48 + lq * 4 + r) * 16 + lr] = acc3[r];
            }
        }
        __syncthreads();

        if (work) {
            float hn[4];
            #pragma unroll
            for (int r = 0; r < 4; ++r) {
                float iv = xchf[0 * 1024 + b_ep * 16 + q4 + r] + bias[0][r];
                float fv = xchf[1 * 1024 + b_ep * 16 + q4 + r] + bias[1][r];
                float gv = xchf[2 * 1024 + b_ep * 16 + q4 + r] + bias[2][r];
                float ov = xchf[3 * 1024 + b_ep * 16 + q4 + r] + bias[3][r];
                float ig = 1.f / (1.f + __expf(-iv));
                float fg = 1.f / (1.f + __expf(-fv));
                float og = 1.f / (1.f + __expf(-ov));
                float gg = tanhf(gv);
                float cn = fg * creg[r] + ig * gg;
                creg[r] = cn;
                hn[r] = og * tanhf(cn);
            }
            // h publish: write-through to coherence point
            ushort_t* hw = layer ? (h1 + rp * (B_ * H_)) : (h0 + wpar * (B_ * H_));
            u32x2 hv;
            hv.x = (unsigned)f2bf(hn[0]) | ((unsigned)f2bf(hn[1]) << 16);
            hv.y = (unsigned)f2bf(hn[2]) | ((unsigned)f2bf(hn[3]) << 16);
            store8_sys(hw + b_ep * H_ + col0, hv);

            float4v o4 = {hn[0], hn[1], hn[2], hn[3]};
            if (layer) {
                __builtin_nontemporal_store(o4,
                    (float4v*)(dout + 8192 + ((size_t)b_ep * T_ + t) * H_ + col0));
            }
            if (t == 511) {
                float4v c4 = {creg[0], creg[1], creg[2], creg[3]};
                __builtin_nontemporal_store(o4,
                    (float4v*)(dout + 16785408 + (size_t)layer * (B_ * H_) + b_ep * H_ + col0));
                __builtin_nontemporal_store(c4,
                    (float4v*)(dout + 16850944 + (size_t)layer * (B_ * H_) + b_ep * H_ + col0));
            }
        }

        // ---- flag release + join (no cache maintenance) ----
        asm volatile("s_waitcnt vmcnt(0)" ::: "memory");
        __syncthreads();
        if (tid == 0) {
            asm volatile("buffer_wbl2 sc0 sc1\n\ts_waitcnt vmcnt(0)" ::: "memory");
            unsigned fv = (unsigned)(s + 1);
            asm volatile("global_store_dword %0, %1, off sc0 sc1"
                         :: "v"(flags + blk), "v"(fv) : "memory");
        }
        if (tid < NBLK) {
            const unsigned* fp = flags + tid;
            while (load_flag_sys(fp) < (unsigned)(s + 1)) { }
        }
        __syncthreads();
    }
}

// ---- final projection: out = h1T @ W_out^T + b_out -----------------------
__global__ void out_gemm(const float* __restrict__ h1T, const float* __restrict__ wout,
                         const float* __restrict__ bout, float* __restrict__ out) {
    int b = blockIdx.x, o = threadIdx.x;
    const float* hr = h1T + (size_t)b * 512;
    const float* wr = wout + (size_t)o * 512;
    float acc = bout[o];
    #pragma unroll 8
    for (int k = 0; k < 512; ++k) acc += hr[k] * wr[k];
    out[b * 128 + o] = acc;
}

extern "C" void kernel_launch(void* const* d_in, const int* in_sizes, int n_in,
                              void* d_out, int out_size, void* d_ws, size_t ws_size,
                              hipStream_t stream)
{
    const float* x    = (const float*)d_in[0];
    const float* wih0 = (const float*)d_in[1];
    const float* whh0 = (const float*)d_in[2];
    const float* bih0 = (const float*)d_in[3];
    const float* bhh0 = (const float*)d_in[4];
    const float* wih1 = (const float*)d_in[5];
    const float* whh1 = (const float*)d_in[6];
    const float* bih1 = (const float*)d_in[7];
    const float* bhh1 = (const float*)d_in[8];
    const float* wout = (const float*)d_in[9];
    const float* bout = (const float*)d_in[10];
    float* out = (float*)d_out;

    char* ws = (char*)d_ws;
    ushort_t* xbf   = (ushort_t*)(ws);
    ushort_t* wp0   = (ushort_t*)(ws + 16777216);
    ushort_t* wp1   = (ushort_t*)(ws + 19922944);
    ushort_t* h0    = (ushort_t*)(ws + 24117248);
    ushort_t* h1    = (ushort_t*)(ws + 24248320);
    unsigned* flags = (unsigned*)(ws + 24379392);

    (void)hipFuncSetAttribute((const void*)lstm_persist,
                              hipFuncAttributeMaxDynamicSharedMemorySize, 147456);

    conv_x<<<8192, 256, 0, stream>>>(x, xbf);
    pack_w<<<4096, 256, 0, stream>>>(wih0, whh0, wih1, whh1, wp0, wp1);
    zero_ws<<<65, 256, 0, stream>>>((uint4*)(ws + 24117248));

    lstm_persist<<<NBLK, 256, 147456, stream>>>(xbf, wp0, wp1, h0, h1,
                                                bih0, bhh0, bih1, bhh1, out, flags);

    out_gemm<<<64, 128, 0, stream>>>(out + 16785408 + B_ * H_, wout, bout, out);
}

// Round 5
// 5495.561 us; speedup vs baseline: 1.9172x; 1.1187x over previous
//
#include <hip/hip_runtime.h>

// LSTM B=64,T=512,I=256,H=512,L=2,O=128. fp32 in/out, bf16 MFMA compute.
//
// R5 = R4 minus buffer_wbl2 (full-L2 walk per block per step — the stall),
// plus split staged/done flags so layer0 runs ahead of layer1 (WAR hazard on
// the h0 plane releases at L1's staging, not L1's step end), plus expf-tanh.
//
// Persistent kernel, flag-based grid sync, no cache-maintenance ops at all.
// h exchange through the coherence point (MALL):
//   producers: global_store sc0 sc1 (write-through), vmcnt drain, flag sc0 sc1
//   consumers: poll flags sc0 sc1, stage h planes into LDS via
//              global_load_dwordx4 sc0 sc1 (bypass L1/L2 -> always fresh)
// x/weights/biases stay normally cached (nothing invalidates them).
//
// Block b: layer=b>>5, n2=b&31 -> 16 gate-cols x 4 strips, all 64 batches.
// Wave wv = gate strip; 4 batch-tiles of 16. Weights in registers.
// LDS: buf0 64KB (h plane), buf1 64KB (layer1 second plane), xch 16KB.
//
// ws layout (bytes):
//   0         xT_bf16 [512][64][256] bf16   16,777,216
//   16777216  Wpack0  [2048][768]    bf16    3,145,728
//   19922944  Wpack1  [2048][1024]   bf16    4,194,304
//   24117248  h0 planes[2][64][512]  bf16      131,072
//   24248320  h1 planes[2][64][512]  bf16      131,072
//   24379392  sflag   [64] uint                    256
//   24379648  dflag   [64] uint                    256

#define B_  64
#define T_  512
#define I0_ 256
#define H_  512
#define NBLK 64

typedef unsigned short ushort_t;
typedef __attribute__((ext_vector_type(8))) short        short8;
typedef __attribute__((ext_vector_type(4))) float        float4v;
typedef __attribute__((ext_vector_type(4))) unsigned int u32x4;
typedef __attribute__((ext_vector_type(2))) unsigned int u32x2;

__device__ __forceinline__ unsigned short f2bf(float f) {
    unsigned int u = __builtin_bit_cast(unsigned int, f);
    u += 0x7fffu + ((u >> 16) & 1u);           // RTNE
    return (unsigned short)(u >> 16);
}

__device__ __forceinline__ float ftanh(float x) {
    float e = __expf(2.f * x);                 // saturates correctly at +/-inf
    return 1.f - 2.f / (e + 1.f);
}

// ---- prologue: x fp32 [B][T][I] -> bf16 transposed [T][B][I] -------------
__global__ void conv_x(const float* __restrict__ x, ushort_t* __restrict__ xb) {
    size_t idx4 = ((size_t)blockIdx.x * 256 + threadIdx.x) * 4;
    float4 v = *(const float4*)(x + idx4);
    size_t b = idx4 >> 17;
    size_t rem = idx4 & 131071;
    size_t t = rem >> 8;
    size_t i = rem & 255;
    ushort4 o;
    o.x = f2bf(v.x); o.y = f2bf(v.y); o.z = f2bf(v.z); o.w = f2bf(v.w);
    *(ushort4*)(xb + (((t * B_) + b) << 8) + i) = o;
}

// ---- prologue: pack [W_ih | W_hh] -> bf16, rows grouped per col-group ----
__global__ void pack_w(const float* __restrict__ wih0, const float* __restrict__ whh0,
                       const float* __restrict__ wih1, const float* __restrict__ whh1,
                       ushort_t* __restrict__ wp0, ushort_t* __restrict__ wp1) {
    int p = blockIdx.x;
    int layer = p >> 11;
    int row = p & 2047;
    int n = row >> 6, rem = row & 63;
    int st = rem >> 4, jj = rem & 15;
    int g = st * 512 + n * 16 + jj;
    if (layer == 0) {
        for (int k = threadIdx.x; k < 768; k += 256) {
            float v = (k < 256) ? wih0[(size_t)g * 256 + k]
                                : whh0[(size_t)g * 512 + (k - 256)];
            wp0[(size_t)row * 768 + k] = f2bf(v);
        }
    } else {
        for (int k = threadIdx.x; k < 1024; k += 256) {
            float v = (k < 512) ? wih1[(size_t)g * 512 + k]
                                : whh1[(size_t)g * 512 + (k - 512)];
            wp1[(size_t)row * 1024 + k] = f2bf(v);
        }
    }
}

// ---- prologue: zero h planes + flags (262656 B -> 16416 uint4) -----------
__global__ void zero_ws(uint4* p) {
    size_t i = (size_t)blockIdx.x * 256 + threadIdx.x;
    if (i < 16416) p[i] = uint4{0, 0, 0, 0};
}

// ---- system-scope (coherence-point) helpers ------------------------------
__device__ __forceinline__ void store8_sys(void* p, u32x2 v) {
    asm volatile("global_store_dwordx2 %0, %1, off sc0 sc1" :: "v"(p), "v"(v) : "memory");
}
__device__ __forceinline__ void store_flag_sys(unsigned* p, unsigned v) {
    asm volatile("global_store_dword %0, %1, off sc0 sc1" :: "v"(p), "v"(v) : "memory");
}
__device__ __forceinline__ unsigned load_flag_sys(const unsigned* p) {
    unsigned r;
    asm volatile("global_load_dword %0, %1, off sc0 sc1\n\ts_waitcnt vmcnt(0)"
                 : "=v"(r) : "v"(p) : "memory");
    return r;
}

// stage one 64KB h plane (64 rows x 512 cols bf16) into LDS, chunked layout:
// LDS uint4-index = kc*64 + row (kc = k/8). Thread: row=tid>>2, kc base=(tid&3)*16.
__device__ __forceinline__ void stage_plane(const ushort_t* plane, ushort_t* lds, int tid) {
    const ushort_t* ga = plane + (tid >> 2) * 512 + (tid & 3) * 128;
    u32x4 t0,t1,t2,t3,t4,t5,t6,t7,t8,t9,t10,t11,t12,t13,t14,t15;
    asm volatile(
        "global_load_dwordx4 %0,  %16, off sc0 sc1\n\t"
        "global_load_dwordx4 %1,  %16, off offset:16 sc0 sc1\n\t"
        "global_load_dwordx4 %2,  %16, off offset:32 sc0 sc1\n\t"
        "global_load_dwordx4 %3,  %16, off offset:48 sc0 sc1\n\t"
        "global_load_dwordx4 %4,  %16, off offset:64 sc0 sc1\n\t"
        "global_load_dwordx4 %5,  %16, off offset:80 sc0 sc1\n\t"
        "global_load_dwordx4 %6,  %16, off offset:96 sc0 sc1\n\t"
        "global_load_dwordx4 %7,  %16, off offset:112 sc0 sc1\n\t"
        "global_load_dwordx4 %8,  %16, off offset:128 sc0 sc1\n\t"
        "global_load_dwordx4 %9,  %16, off offset:144 sc0 sc1\n\t"
        "global_load_dwordx4 %10, %16, off offset:160 sc0 sc1\n\t"
        "global_load_dwordx4 %11, %16, off offset:176 sc0 sc1\n\t"
        "global_load_dwordx4 %12, %16, off offset:192 sc0 sc1\n\t"
        "global_load_dwordx4 %13, %16, off offset:208 sc0 sc1\n\t"
        "global_load_dwordx4 %14, %16, off offset:224 sc0 sc1\n\t"
        "global_load_dwordx4 %15, %16, off offset:240 sc0 sc1\n\t"
        "s_waitcnt vmcnt(0)"
        : "=&v"(t0),"=&v"(t1),"=&v"(t2),"=&v"(t3),"=&v"(t4),"=&v"(t5),"=&v"(t6),"=&v"(t7),
          "=&v"(t8),"=&v"(t9),"=&v"(t10),"=&v"(t11),"=&v"(t12),"=&v"(t13),"=&v"(t14),"=&v"(t15)
        : "v"(ga)
        : "memory");
    u32x4* lw = (u32x4*)lds + (tid & 3) * 1024 + (tid >> 2);
    lw[0*64]=t0;  lw[1*64]=t1;  lw[2*64]=t2;  lw[3*64]=t3;
    lw[4*64]=t4;  lw[5*64]=t5;  lw[6*64]=t6;  lw[7*64]=t7;
    lw[8*64]=t8;  lw[9*64]=t9;  lw[10*64]=t10; lw[11*64]=t11;
    lw[12*64]=t12; lw[13*64]=t13; lw[14*64]=t14; lw[15*64]=t15;
}

// ---- persistent LSTM kernel ----------------------------------------------
extern __shared__ ushort_t smem[];

__global__ __launch_bounds__(256, 1) void lstm_persist(
    const ushort_t* __restrict__ xbf,
    const ushort_t* __restrict__ wp0,
    const ushort_t* __restrict__ wp1,
    ushort_t* __restrict__ h0,
    ushort_t* __restrict__ h1,
    const float* __restrict__ bi0, const float* __restrict__ bh0,
    const float* __restrict__ bi1, const float* __restrict__ bh1,
    float* __restrict__ dout,
    unsigned* __restrict__ sflag,
    unsigned* __restrict__ dflag)
{
    const int blk   = blockIdx.x;
    const int layer = blk >> 5;
    const int n2    = blk & 31;
    const int tid   = threadIdx.x;
    const int lane  = tid & 63;
    const int wv    = tid >> 6;      // gate strip 0=i 1=f 2=g 3=o
    const int lr    = lane & 15;
    const int lq    = lane >> 4;

    ushort_t* buf0 = smem;                   // 64KB
    ushort_t* buf1 = smem + 32768;           // 64KB
    float*    xchf = (float*)(smem + 65536); // 16KB

    // ---- preload this wave's weight slice into registers ----
    short8 bf[32];
    if (layer) {
        const ushort_t* bp = wp1 + (size_t)(n2 * 64 + wv * 16 + lr) * 1024 + lq * 8;
        #pragma unroll
        for (int kc = 0; kc < 32; ++kc) bf[kc] = *(const short8*)(bp + kc * 32);
    } else {
        const ushort_t* bp = wp0 + (size_t)(n2 * 64 + wv * 16 + lr) * 768 + lq * 8;
        #pragma unroll
        for (int kc = 0; kc < 24; ++kc) bf[kc] = *(const short8*)(bp + kc * 32);
    }

    // ---- epilogue role: thread owns batch b_ep, 4 cols q4..q4+3 ----------
    const int b_ep = tid >> 2;
    const int q4   = (tid & 3) * 4;
    const int col0 = n2 * 16 + q4;
    const float* bi = layer ? bi1 : bi0;
    const float* bh = layer ? bh1 : bh0;
    float bias[4][4];
    #pragma unroll
    for (int g = 0; g < 4; ++g)
        #pragma unroll
        for (int r = 0; r < 4; ++r)
            bias[g][r] = bi[g * 512 + col0 + r] + bh[g * 512 + col0 + r];
    float creg[4] = {0.f, 0.f, 0.f, 0.f};

    // poll target: L0 waits {dflag[L0], sflag[L1]}; L1 waits dflag[all]
    const unsigned* pollp = (layer == 0 && tid >= 32) ? (sflag + tid) : (dflag + tid);

    #pragma unroll 1
    for (int s = 0; s < 513; ++s) {
        const bool work = layer ? (s >= 1) : (s < 512);
        const int  t    = layer ? (s - 1) : s;
        const int  rp   = (s + 1) & 1;
        const int  wpar = s & 1;

        // ---- wait for prior-step dependencies ----
        if (s > 0) {
            if (tid < NBLK) {
                const unsigned need = (unsigned)s;
                while (load_flag_sys(pollp) < need) { }
            }
            __syncthreads();
        }

        // ---- stage h planes into LDS (coherence-point loads) ----
        if (work) {
            stage_plane(h0 + rp * (B_ * H_), buf0, tid);
            if (layer) stage_plane(h1 + wpar * (B_ * H_), buf1, tid);
        }
        __syncthreads();
        if (tid == 0) store_flag_sys(sflag + blk, (unsigned)(s + 1));

        if (work) {
            float4v acc0 = {0.f,0.f,0.f,0.f}, acc1 = {0.f,0.f,0.f,0.f};
            float4v acc2 = {0.f,0.f,0.f,0.f}, acc3 = {0.f,0.f,0.f,0.f};

            if (layer == 0) {
                const ushort_t* aB = xbf + ((size_t)s * B_ + lr) * I0_ + lq * 8;
                #pragma unroll
                for (int kc = 0; kc < 8; ++kc) {
                    short8 a0 = *(const short8*)(aB + kc * 32);
                    short8 a1 = *(const short8*)(aB + 16 * I0_ + kc * 32);
                    short8 a2 = *(const short8*)(aB + 32 * I0_ + kc * 32);
                    short8 a3 = *(const short8*)(aB + 48 * I0_ + kc * 32);
                    acc0 = __builtin_amdgcn_mfma_f32_16x16x32_bf16(a0, bf[kc], acc0, 0, 0, 0);
                    acc1 = __builtin_amdgcn_mfma_f32_16x16x32_bf16(a1, bf[kc], acc1, 0, 0, 0);
                    acc2 = __builtin_amdgcn_mfma_f32_16x16x32_bf16(a2, bf[kc], acc2, 0, 0, 0);
                    acc3 = __builtin_amdgcn_mfma_f32_16x16x32_bf16(a3, bf[kc], acc3, 0, 0, 0);
                }
                #pragma unroll
                for (int c = 0; c < 16; ++c) {
                    const int base = ((c * 4 + lq) * 64 + lr) * 8;
                    short8 a0 = *(const short8*)(buf0 + base);
                    short8 a1 = *(const short8*)(buf0 + base + 16 * 8);
                    short8 a2 = *(const short8*)(buf0 + base + 32 * 8);
                    short8 a3 = *(const short8*)(buf0 + base + 48 * 8);
                    acc0 = __builtin_amdgcn_mfma_f32_16x16x32_bf16(a0, bf[8 + c], acc0, 0, 0, 0);
                    acc1 = __builtin_amdgcn_mfma_f32_16x16x32_bf16(a1, bf[8 + c], acc1, 0, 0, 0);
                    acc2 = __builtin_amdgcn_mfma_f32_16x16x32_bf16(a2, bf[8 + c], acc2, 0, 0, 0);
                    acc3 = __builtin_amdgcn_mfma_f32_16x16x32_bf16(a3, bf[8 + c], acc3, 0, 0, 0);
                }
            } else {
                #pragma unroll
                for (int c = 0; c < 16; ++c) {
                    const int base = ((c * 4 + lq) * 64 + lr) * 8;
                    short8 a0 = *(const short8*)(buf0 + base);
                    short8 a1 = *(const short8*)(buf0 + base + 16 * 8);
                    short8 a2 = *(const short8*)(buf0 + base + 32 * 8);
                    short8 a3 = *(const short8*)(buf0 + base + 48 * 8);
                    acc0 = __builtin_amdgcn_mfma_f32_16x16x32_bf16(a0, bf[c], acc0, 0, 0, 0);
                    acc1 = __builtin_amdgcn_mfma_f32_16x16x32_bf16(a1, bf[c], acc1, 0, 0, 0);
                    acc2 = __builtin_amdgcn_mfma_f32_16x16x32_bf16(a2, bf[c], acc2, 0, 0, 0);
                    acc3 = __builtin_amdgcn_mfma_f32_16x16x32_bf16(a3, bf[c], acc3, 0, 0, 0);
                }
                #pragma unroll
                for (int c = 0; c < 16; ++c) {
                    const int base = ((c * 4 + lq) * 64 + lr) * 8;
                    short8 a0 = *(const short8*)(buf1 + base);
                    short8 a1 = *(const short8*)(buf1 + base + 16 * 8);
                    short8 a2 = *(const short8*)(buf1 + base + 32 * 8);
                    short8 a3 = *(const short8*)(buf1 + base + 48 * 8);
                    acc0 = __builtin_amdgcn_mfma_f32_16x16x32_bf16(a0, bf[16 + c], acc0, 0, 0, 0);
                    acc1 = __builtin_amdgcn_mfma_f32_16x16x32_bf16(a1, bf[16 + c], acc1, 0, 0, 0);
                    acc2 = __builtin_amdgcn_mfma_f32_16x16x32_bf16(a2, bf[16 + c], acc2, 0, 0, 0);
                    acc3 = __builtin_amdgcn_mfma_f32_16x16x32_bf16(a3, bf[16 + c], acc3, 0, 0, 0);
                }
            }
            // D layout: col=lane&15, row=(lane>>4)*4+reg
            #pragma unroll
            for (int r = 0; r < 4; ++r) {
                xchf[wv * 1024 + ( 0 + lq * 4 + r) * 16 + lr] = acc0[r];
                xchf[wv * 1024 + (16 + lq * 4 + r) * 16 + lr] = acc1[r];
                xchf[wv * 1024 + (32 + lq * 4 + r) * 16 + lr] = acc2[r];
                xchf[wv * 1024 + (48 + lq * 4 + r) * 16 + lr] = acc3[r];
            }
        }
        __syncthreads();

        if (work) {
            float hn[4];
            #pragma unroll
            for (int r = 0; r < 4; ++r) {
                float iv = xchf[0 * 1024 + b_ep * 16 + q4 + r] + bias[0][r];
                float fv = xchf[1 * 1024 + b_ep * 16 + q4 + r] + bias[1][r];
                float gv = xchf[2 * 1024 + b_ep * 16 + q4 + r] + bias[2][r];
                float ov = xchf[3 * 1024 + b_ep * 16 + q4 + r] + bias[3][r];
                float ig = 1.f / (1.f + __expf(-iv));
                float fg = 1.f / (1.f + __expf(-fv));
                float og = 1.f / (1.f + __expf(-ov));
                float gg = ftanh(gv);
                float cn = fg * creg[r] + ig * gg;
                creg[r] = cn;
                hn[r] = og * ftanh(cn);
            }
            // h publish: write-through to coherence point
            ushort_t* hw = layer ? (h1 + rp * (B_ * H_)) : (h0 + wpar * (B_ * H_));
            u32x2 hv;
            hv.x = (unsigned)f2bf(hn[0]) | ((unsigned)f2bf(hn[1]) << 16);
            hv.y = (unsigned)f2bf(hn[2]) | ((unsigned)f2bf(hn[3]) << 16);
            store8_sys(hw + b_ep * H_ + col0, hv);

            float4v o4 = {hn[0], hn[1], hn[2], hn[3]};
            if (layer) {
                __builtin_nontemporal_store(o4,
                    (float4v*)(dout + 8192 + ((size_t)b_ep * T_ + t) * H_ + col0));
            }
            if (t == 511) {
                float4v c4 = {creg[0], creg[1], creg[2], creg[3]};
                __builtin_nontemporal_store(o4,
                    (float4v*)(dout + 16785408 + (size_t)layer * (B_ * H_) + b_ep * H_ + col0));
                __builtin_nontemporal_store(c4,
                    (float4v*)(dout + 16850944 + (size_t)layer * (B_ * H_) + b_ep * H_ + col0));
            }
        }

        // ---- release: drain publish stores, then done-flag ----
        asm volatile("s_waitcnt vmcnt(0)" ::: "memory");
        __syncthreads();
        if (tid == 0) store_flag_sys(dflag + blk, (unsigned)(s + 1));
    }
}

// ---- final projection: out = h1T @ W_out^T + b_out -----------------------
__global__ void out_gemm(const float* __restrict__ h1T, const float* __restrict__ wout,
                         const float* __restrict__ bout, float* __restrict__ out) {
    int b = blockIdx.x, o = threadIdx.x;
    const float* hr = h1T + (size_t)b * 512;
    const float* wr = wout + (size_t)o * 512;
    float acc = bout[o];
    #pragma unroll 8
    for (int k = 0; k < 512; ++k) acc += hr[k] * wr[k];
    out[b * 128 + o] = acc;
}

extern "C" void kernel_launch(void* const* d_in, const int* in_sizes, int n_in,
                              void* d_out, int out_size, void* d_ws, size_t ws_size,
                              hipStream_t stream)
{
    const float* x    = (const float*)d_in[0];
    const float* wih0 = (const float*)d_in[1];
    const float* whh0 = (const float*)d_in[2];
    const float* bih0 = (const float*)d_in[3];
    const float* bhh0 = (const float*)d_in[4];
    const float* wih1 = (const float*)d_in[5];
    const float* whh1 = (const float*)d_in[6];
    const float* bih1 = (const float*)d_in[7];
    const float* bhh1 = (const float*)d_in[8];
    const float* wout = (const float*)d_in[9];
    const float* bout = (const float*)d_in[10];
    float* out = (float*)d_out;

    char* ws = (char*)d_ws;
    ushort_t* xbf   = (ushort_t*)(ws);
    ushort_t* wp0   = (ushort_t*)(ws + 16777216);
    ushort_t* wp1   = (ushort_t*)(ws + 19922944);
    ushort_t* h0    = (ushort_t*)(ws + 24117248);
    ushort_t* h1    = (ushort_t*)(ws + 24248320);
    unsigned* sflag = (unsigned*)(ws + 24379392);
    unsigned* dflag = (unsigned*)(ws + 24379648);

    (void)hipFuncSetAttribute((const void*)lstm_persist,
                              hipFuncAttributeMaxDynamicSharedMemorySize, 147456);

    conv_x<<<8192, 256, 0, stream>>>(x, xbf);
    pack_w<<<4096, 256, 0, stream>>>(wih0, whh0, wih1, whh1, wp0, wp1);
    zero_ws<<<65, 256, 0, stream>>>((uint4*)(ws + 24117248));

    lstm_persist<<<NBLK, 256, 147456, stream>>>(xbf, wp0, wp1, h0, h1,
                                                bih0, bhh0, bih1, bhh1, out,
                                                sflag, dflag);

    out_gemm<<<64, 128, 0, stream>>>(out + 16785408 + B_ * H_, wout, bout, out);
}